// Round 4
// baseline (42.012 us; speedup 1.0000x reference)
//
#include <hip/hip_runtime.h>
#include <hip/hip_bf16.h>

// ExtraMSAEmbedding: out[p, o] = W[o, msa[p]] + hd[p]*W[o,23] + dv[p]*W[o,24] + b[o]
// p = flattened (seq, res) position, 2048*384 = 786432 positions, o in [0,64).
// Write-bound: 201 MB f32 output vs ~9.4 MB input reads.
// Measured ceilings: pure-write fill ~7.0 TB/s; D2D copy (mixed R+W) ~6.3 TB/s
// -> floor ~33.5 us. R2/R3 showed: table-init count doesn't matter, nt ~ normal.
// This version: issue the 24 HBM input loads BEFORE table init so read latency
// hides under the LDS build + barrier instead of sitting on the post-sync path.

#define C_IN   25
#define C_OUT  64
#define TPAD   68   // row stride in floats: 272 B, 16B-aligned
#define UNROLL 8    // positions per thread; block covers 128 positions

typedef float v4f __attribute__((ext_vector_type(4)));

__global__ __launch_bounds__(256) void extra_msa_emb_kernel(
    const int* __restrict__ msa,
    const float* __restrict__ hd,
    const float* __restrict__ dv,
    const float* __restrict__ W,   // [64, 25] row-major
    const float* __restrict__ b,   // [64]
    float* __restrict__ out) {     // [npos, 64]
    const int tid   = threadIdx.x;
    const int group = tid >> 4;   // 16 groups; wave w covers groups 4w..4w+3
    const int lane  = tid & 15;   // 16 threads per position
    const int o     = lane * 4;   // each thread owns 4 consecutive outputs

    const int pbase = blockIdx.x * 128 + group;

    // 1) Issue ALL input loads first — HBM miss latency (~900 cy) overlaps
    //    the table build + barrier below.
    int   cls[UNROLL];
    float h[UNROLL], d[UNROLL];
#pragma unroll
    for (int j = 0; j < UNROLL; ++j) {
        const int p = pbase + j * 16;
        cls[j] = msa[p];
        h[j]   = hd[p];
        d[j]   = dv[p];
    }

    // 2) Fused table, transposed + padded: T[c][o] = W[o*25+c] (+ b[o], c<23).
    __shared__ float T[C_IN][TPAD];
    for (int idx = tid; idx < C_IN * C_OUT; idx += 256) {
        const int c = idx >> 6;
        const int oo = idx & 63;
        float v = W[oo * C_IN + c];
        if (c < 23) v += b[oo];
        T[c][oo] = v;
    }
    __syncthreads();

    const v4f w23 = *reinterpret_cast<const v4f*>(&T[23][o]);
    const v4f w24 = *reinterpret_cast<const v4f*>(&T[24][o]);

    v4f t[UNROLL];
#pragma unroll
    for (int j = 0; j < UNROLL; ++j)
        t[j] = *reinterpret_cast<const v4f*>(&T[cls[j]][o]);

    // Wave stores: per j, 64 lanes cover 4 consecutive positions = 1 KB
    // contiguous. Streaming (nt) hint: output is never re-read in-kernel.
#pragma unroll
    for (int j = 0; j < UNROLL; ++j) {
        const v4f r = t[j] + h[j] * w23 + d[j] * w24;
        const long long p = (long long)(pbase + j * 16);
        __builtin_nontemporal_store(r, reinterpret_cast<v4f*>(&out[p * C_OUT + o]));
    }
}

extern "C" void kernel_launch(void* const* d_in, const int* in_sizes, int n_in,
                              void* d_out, int out_size, void* d_ws, size_t ws_size,
                              hipStream_t stream) {
    const int*   msa = (const int*)d_in[0];
    const float* hd  = (const float*)d_in[1];
    const float* dv  = (const float*)d_in[2];
    const float* W   = (const float*)d_in[3];
    const float* b   = (const float*)d_in[4];
    float* out = (float*)d_out;

    const int npos = in_sizes[0];  // 2048 * 384 = 786432, divisible by 128

    const int block = 256;
    const int grid  = npos / 128;  // 6144 blocks, one 128-position chunk each
    extra_msa_emb_kernel<<<grid, block, 0, stream>>>(msa, hd, dv, W, b, out);
}

// Round 5
// 37.684 us; speedup vs baseline: 1.1148x; 1.1148x over previous
//
#include <hip/hip_runtime.h>
#include <hip/hip_bf16.h>

// ExtraMSAEmbedding: out[p, o] = W[o, msa[p]] + hd[p]*W[o,23] + dv[p]*W[o,24] + b[o]
// p = flattened (seq, res) position, 2048*384 = 786432 positions, o in [0,64).
// Write-bound: 201 MB f32 output vs ~9.4 MB input reads. Floor ~33.5 us @ 6.3 TB/s.
// R4 lesson: vmcnt is FIFO — table-init W loads must be issued BEFORE any input
// prefetch, or the table build stalls on all outstanding input loads.
// This version: persistent blocks (grid 1536, 4 iters of 128 pos), software-
// pipelined prefetch so steady-state stores never wait on fresh HBM reads.

#define C_IN   25
#define C_OUT  64
#define TPAD   68   // row stride in floats: 272 B, 16B-aligned
#define UNROLL 8    // positions per thread per iteration; block covers 128/iter

typedef float v4f __attribute__((ext_vector_type(4)));

__global__ __launch_bounds__(256) void extra_msa_emb_kernel(
    const int* __restrict__ msa,
    const float* __restrict__ hd,
    const float* __restrict__ dv,
    const float* __restrict__ W,   // [64, 25] row-major
    const float* __restrict__ b,   // [64]
    float* __restrict__ out,       // [npos, 64]
    int npos) {
    const int tid = threadIdx.x;

    // 1) Table first (its W/b loads are the OLDEST vmem ops — FIFO-safe).
    //    T[c][o] = W[o*25+c] (+ b[o] when c < 23), transposed + padded.
    __shared__ float T[C_IN][TPAD];
    for (int idx = tid; idx < C_IN * C_OUT; idx += 256) {
        const int c  = idx >> 6;
        const int oo = idx & 63;
        float v = W[oo * C_IN + c];
        if (c < 23) v += b[oo];
        T[c][oo] = v;
    }
    __syncthreads();

    const int group = tid >> 4;   // 16 groups; wave w covers groups 4w..4w+3
    const int lane  = tid & 15;   // 16 threads per position
    const int o     = lane * 4;   // each thread owns 4 consecutive outputs

    const v4f w23 = *reinterpret_cast<const v4f*>(&T[23][o]);
    const v4f w24 = *reinterpret_cast<const v4f*>(&T[24][o]);

    const long long stride = (long long)gridDim.x * 128;
    long long base = (long long)blockIdx.x * 128;
    if (base >= npos) return;

    // 2) Prefetch iteration 0.
    int   cls[UNROLL];
    float h[UNROLL], d[UNROLL];
#pragma unroll
    for (int j = 0; j < UNROLL; ++j) {
        const int p = (int)base + group + j * 16;
        cls[j] = msa[p];
        h[j]   = hd[p];
        d[j]   = dv[p];
    }

    // 3) Pipelined loop: issue iter t+1 loads BEFORE consuming iter t.
    for (;;) {
        const long long nbase = base + stride;
        const bool more = (nbase < npos);   // uniform across block

        int   ncls[UNROLL];
        float nh[UNROLL], nd[UNROLL];
        if (more) {
#pragma unroll
            for (int j = 0; j < UNROLL; ++j) {
                const int p = (int)nbase + group + j * 16;
                ncls[j] = msa[p];
                nh[j]   = hd[p];
                nd[j]   = dv[p];
            }
        }

        v4f t[UNROLL];
#pragma unroll
        for (int j = 0; j < UNROLL; ++j)
            t[j] = *reinterpret_cast<const v4f*>(&T[cls[j]][o]);

        // Per j, 64 lanes store 4 consecutive positions = 1 KB contiguous.
#pragma unroll
        for (int j = 0; j < UNROLL; ++j) {
            const v4f r = t[j] + h[j] * w23 + d[j] * w24;
            const long long p = base + group + j * 16;
            __builtin_nontemporal_store(r, reinterpret_cast<v4f*>(&out[p * C_OUT + o]));
        }

        if (!more) break;
        base = nbase;
#pragma unroll
        for (int j = 0; j < UNROLL; ++j) {
            cls[j] = ncls[j];
            h[j]   = nh[j];
            d[j]   = nd[j];
        }
    }
}

extern "C" void kernel_launch(void* const* d_in, const int* in_sizes, int n_in,
                              void* d_out, int out_size, void* d_ws, size_t ws_size,
                              hipStream_t stream) {
    const int*   msa = (const int*)d_in[0];
    const float* hd  = (const float*)d_in[1];
    const float* dv  = (const float*)d_in[2];
    const float* W   = (const float*)d_in[3];
    const float* b   = (const float*)d_in[4];
    float* out = (float*)d_out;

    const int npos = in_sizes[0];  // 2048 * 384 = 786432 = 1536 * 128 * 4

    const int block = 256;
    const int grid  = 1536;  // 6 blocks/CU; each block: 4 pipelined iterations
    extra_msa_emb_kernel<<<grid, block, 0, stream>>>(msa, hd, dv, W, b, out, npos);
}